// Round 1
// baseline (932.433 us; speedup 1.0000x reference)
//
#include <hip/hip_runtime.h>
#include <math.h>

#define D       512
#define KTOP    5
#define CHUNK   32        // refs staged per chunk
#define PAD_ROW 516       // lds row stride (floats): +4 keeps float4 align, staggers banks
#define NB_MAIN 512       // main kernel grid blocks

// ---------------------------------------------------------------------------
// Kernel 1: fused ref-norm + sims + per-block top-5.
//  block = 512 threads = 8 waves. lane l = query l (B=64 == wavefront size).
//  wave w owns d-slice [64w, 64w+64) held in 64 VGPRs per lane.
//  Refs staged to LDS in chunks of 32; sumsq computed during staging.
//  Partial dots reduced across the 8 waves via LDS float atomics.
// ---------------------------------------------------------------------------
__global__ __launch_bounds__(512, 4) void sim_topk_kernel(
    const float* __restrict__ q, const float* __restrict__ refs,
    float* __restrict__ cand_val, int* __restrict__ cand_idx, int N)
{
  __shared__ float lds_ref[CHUNK * PAD_ROW];   // 66048 B; overlaid w/ cand merge at end
  __shared__ float sim_lds[CHUNK * 64];        // 8192 B
  __shared__ float inv_lds[CHUNK];             // 128 B

  const int t = threadIdx.x;
  const int w = t >> 6;          // wave id = d-slice 0..7
  const int l = t & 63;          // lane = query id
  const int dbase = w * 64;

  // Query slice -> registers (one-time; 128 KB/block, L3-resident)
  float qreg[64];
  {
    const float* qp = q + l * D + dbase;
    #pragma unroll
    for (int i = 0; i < 16; ++i) {
      float4 v = *(const float4*)(qp + 4 * i);
      qreg[4*i+0] = v.x; qreg[4*i+1] = v.y; qreg[4*i+2] = v.z; qreg[4*i+3] = v.w;
    }
  }

  float tv[KTOP]; int tix[KTOP];
  #pragma unroll
  for (int j = 0; j < KTOP; ++j) { tv[j] = -INFINITY; tix[j] = 0; }

  const int nchunks = (N + CHUNK - 1) / CHUNK;
  for (int c = blockIdx.x; c < nchunks; c += gridDim.x) {
    const int base = c * CHUNK;
    __syncthreads();                       // protect LDS reuse across iterations

    // zero sim accumulators
    #pragma unroll
    for (int i = 0; i < (CHUNK * 64) / 512; ++i) sim_lds[t + 512 * i] = 0.f;

    // stage 32 refs -> LDS (coalesced 256B segments) + fused sumsq
    {
      const int rr  = t >> 4;              // ref-in-chunk 0..31 (16 threads each)
      const int sub = t & 15;
      const int g   = base + rr;
      float ss = 0.f;
      if (g < N) {
        const float* rp = refs + (size_t)g * D + sub * 4;
        #pragma unroll
        for (int i = 0; i < 8; ++i) {
          float4 v = *(const float4*)(rp + 64 * i);
          *(float4*)&lds_ref[rr * PAD_ROW + sub * 4 + 64 * i] = v;
          ss = fmaf(v.x, v.x, ss); ss = fmaf(v.y, v.y, ss);
          ss = fmaf(v.z, v.z, ss); ss = fmaf(v.w, v.w, ss);
        }
      }
      // reduce sumsq across the 16 staging threads (contiguous lanes)
      ss += __shfl_xor(ss, 1); ss += __shfl_xor(ss, 2);
      ss += __shfl_xor(ss, 4); ss += __shfl_xor(ss, 8);
      if (sub == 0) inv_lds[rr] = 1.0f / fmaxf(sqrtf(ss), 1e-12f);
    }
    __syncthreads();

    // partial dots: per ref, 16 broadcast ds_read_b128 + 64 FMAs per wave
    for (int rr = 0; rr < CHUNK; ++rr) {
      const float* rbase = &lds_ref[rr * PAD_ROW + dbase];
      float p0 = 0.f, p1 = 0.f, p2 = 0.f, p3 = 0.f;
      #pragma unroll
      for (int i = 0; i < 16; ++i) {
        float4 rv = *(const float4*)(rbase + 4 * i);
        p0 = fmaf(rv.x, qreg[4*i+0], p0);
        p1 = fmaf(rv.y, qreg[4*i+1], p1);
        p2 = fmaf(rv.z, qreg[4*i+2], p2);
        p3 = fmaf(rv.w, qreg[4*i+3], p3);
      }
      atomicAdd(&sim_lds[rr * 64 + l], (p0 + p1) + (p2 + p3));
    }
    __syncthreads();

    // top-5 update: wave w owns refs rr == w (mod 8)
    #pragma unroll
    for (int k2 = 0; k2 < CHUNK / 8; ++k2) {
      const int rr = w + 8 * k2;
      const int g  = base + rr;
      if (g < N) {
        float v = sim_lds[rr * 64 + l] * inv_lds[rr];
        int  id = g;
        #pragma unroll
        for (int j = 0; j < KTOP; ++j) {
          bool gt = v > tv[j];
          float ov = tv[j]; int oi = tix[j];
          tv[j]  = gt ? v  : ov;  tix[j] = gt ? id : oi;
          v      = gt ? ov : v;   id     = gt ? oi : id;
        }
      }
    }
  }

  // in-block merge of the 8 per-wave lists (overlay lds_ref storage)
  __syncthreads();
  float* cval = lds_ref;                       // 8*5*64 floats = 10240 B
  int*   cidx = (int*)(lds_ref + 8 * KTOP * 64);
  #pragma unroll
  for (int j = 0; j < KTOP; ++j) {
    cval[(w * KTOP + j) * 64 + l] = tv[j];
    cidx[(w * KTOP + j) * 64 + l] = tix[j];
  }
  __syncthreads();
  if (w == 0) {
    float bv[KTOP]; int bi[KTOP];
    #pragma unroll
    for (int j = 0; j < KTOP; ++j) { bv[j] = -INFINITY; bi[j] = 0; }
    for (int s = 0; s < 8 * KTOP; ++s) {
      float v = cval[s * 64 + l]; int id = cidx[s * 64 + l];
      #pragma unroll
      for (int j = 0; j < KTOP; ++j) {
        bool gt = v > bv[j];
        float ov = bv[j]; int oi = bi[j];
        bv[j] = gt ? v  : ov;  bi[j] = gt ? id : oi;
        v     = gt ? ov : v;   id    = gt ? oi : id;
      }
    }
    #pragma unroll
    for (int j = 0; j < KTOP; ++j) {
      cand_val[(size_t)l * (NB_MAIN * KTOP) + blockIdx.x * KTOP + j] = bv[j];
      cand_idx[(size_t)l * (NB_MAIN * KTOP) + blockIdx.x * KTOP + j] = bi[j];
    }
  }
}

// ---------------------------------------------------------------------------
// Kernel 2: per-query merge of NB_MAIN*5 candidates + image gather.
// One block per query.
// ---------------------------------------------------------------------------
__global__ __launch_bounds__(256) void merge_gather_kernel(
    const float* __restrict__ cand_val, const int* __restrict__ cand_idx,
    const float* __restrict__ imgs, float* __restrict__ out)
{
  __shared__ float lval[256 * KTOP];
  __shared__ int   lidx[256 * KTOP];
  const int qn = blockIdx.x;
  const int t  = threadIdx.x;
  const int NC = NB_MAIN * KTOP;           // 2560 candidates per query

  const float* cv = cand_val + (size_t)qn * NC;
  const int*   ci = cand_idx + (size_t)qn * NC;
  float bv[KTOP]; int bi[KTOP];
  #pragma unroll
  for (int j = 0; j < KTOP; ++j) { bv[j] = -INFINITY; bi[j] = 0x7fffffff; }
  for (int i = t; i < NC; i += 256) {
    float v = cv[i]; int id = ci[i];
    #pragma unroll
    for (int j = 0; j < KTOP; ++j) {
      bool gt = (v > bv[j]) || (v == bv[j] && id < bi[j]);
      float ov = bv[j]; int oi = bi[j];
      bv[j] = gt ? v  : ov;  bi[j] = gt ? id : oi;
      v     = gt ? ov : v;   id    = gt ? oi : id;
    }
  }
  #pragma unroll
  for (int j = 0; j < KTOP; ++j) { lval[t*KTOP+j] = bv[j]; lidx[t*KTOP+j] = bi[j]; }
  __syncthreads();

  // tree-merge sorted-5 lists: 256 -> 1
  for (int off = 128; off >= 1; off >>= 1) {
    if (t < off) {
      float ov[KTOP]; int oi[KTOP];
      int i = 0, j = 0;
      #pragma unroll
      for (int n = 0; n < KTOP; ++n) {
        float av  = lval[t * KTOP + i],  bvv = lval[(t + off) * KTOP + j];
        int   ai  = lidx[t * KTOP + i],  bii = lidx[(t + off) * KTOP + j];
        bool  ta  = (av > bvv) || (av == bvv && ai <= bii);
        ov[n] = ta ? av : bvv; oi[n] = ta ? ai : bii;
        i += ta; j += !ta;
      }
      #pragma unroll
      for (int n = 0; n < KTOP; ++n) { lval[t*KTOP+n] = ov[n]; lidx[t*KTOP+n] = oi[n]; }
    }
    __syncthreads();
  }

  // gather 5 images (3072 floats each), coalesced float4 copy
  #pragma unroll
  for (int j = 0; j < KTOP; ++j) {
    int id = lidx[j];   // thread 0's final list
    const float4* s   = (const float4*)(imgs + (size_t)id * 3072);
    float4*       dst = (float4*)(out + (size_t)qn * (KTOP * 3072) + j * 3072);
    for (int e = t; e < 768; e += 256) dst[e] = s[e];
  }
}

extern "C" void kernel_launch(void* const* d_in, const int* in_sizes, int n_in,
                              void* d_out, int out_size, void* d_ws, size_t ws_size,
                              hipStream_t stream) {
  const float* q    = (const float*)d_in[0];   // [64, 512]
  const float* refs = (const float*)d_in[1];   // [N, 512]
  const float* imgs = (const float*)d_in[2];   // [N, 3072]
  const int N = in_sizes[1] / D;               // 50000

  float* cand_val = (float*)d_ws;                                    // 64*NB*5 floats
  int*   cand_idx = (int*)((char*)d_ws + sizeof(float) * 64 * NB_MAIN * KTOP);

  sim_topk_kernel<<<NB_MAIN, 512, 0, stream>>>(q, refs, cand_val, cand_idx, N);
  merge_gather_kernel<<<64, 256, 0, stream>>>(cand_val, cand_idx, imgs, (float*)d_out);
}